// Round 5
// baseline (180.517 us; speedup 1.0000x reference)
//
#include <hip/hip_runtime.h>

// PolylineEncoder: h = relu(X@W1+b1); feat = h@W2+b2; masked max over N=64 points.
// B=32 P=512 N=64 C=9 H=128.  Block = 2 polylines (128 points), grid 8192.
// R5: bias folded into MFMA acc init; packed f32 epilogue/pool (v_pk_*);
// XOR-swizzled Hb (no pad) -> LDS = 32768 B exactly -> 5 blocks/CU;
// Xs & P union inside Hb; mask read directly (1 cache line per wave), no prep2.

using bf16x8 = __attribute__((ext_vector_type(8))) short;
using f32x4  = __attribute__((ext_vector_type(4))) float;

#define MFMA32(A,B,C) __builtin_amdgcn_mfma_f32_16x16x32_bf16((A),(B),(C),0,0,0)

__device__ __forceinline__ f32x4 vmax4(f32x4 a, f32x4 b) {
  return __builtin_elementwise_max(a, b);
}

__device__ __forceinline__ unsigned short f2bf(float f) {
  union { float f; unsigned int u; } v; v.f = f;
  unsigned int r = v.u + 0x7fffu + ((v.u >> 16) & 1u);  // RNE
  return (unsigned short)(r >> 16);
}

// pack two floats to bf16x2 (round-half-up) via v_perm: 3 VALU per 2 elems
__device__ __forceinline__ unsigned int pack_bf2(float a, float b) {
  union { float f; unsigned int u; } ua, ub; ua.f = a; ub.f = b;
  return __builtin_amdgcn_perm(ub.u + 0x8000u, ua.u + 0x8000u, 0x07060302u);
}

// ---------------- prep1: mask sniff + frag-swizzled weights ----------------
// ws: w1sw @0 (8KB) | w2sw @8192 (32KB) | flag @40960
__global__ void prep1(const float* __restrict__ W1, const float* __restrict__ W2,
                      const void* __restrict__ mask,
                      unsigned short* __restrict__ w1sw, unsigned short* __restrict__ w2sw,
                      int* __restrict__ flag) {
  int b = blockIdx.x, t = threadIdx.x;
  if (b == 0) {                      // mask storage sniff over 4096 bytes
    __shared__ int cnt;
    if (t == 0) cnt = 0;
    __syncthreads();
    const unsigned char* mb = (const unsigned char*)mask;
    int local = 0;
    for (int i = t * 16; i < t * 16 + 16; i++) local += (mb[i] != 0) ? 1 : 0;
    atomicAdd(&cnt, local);
    __syncthreads();
    if (t == 0) *flag = (cnt > 2800) ? 1 : 0;   // 1 = byte-wise mask, else int32-wise
  } else if (b <= 2) {
    // w1 A-frags (16x16x32): entry e = (wr*4+th)*64 + lane; h=(e>>6)*16+(lane&15)
    int e = (b - 1) * 256 + t;       // 512 entries x 8 halves = 8KB
    int lane = e & 63, grp = e >> 6;
    int li = lane & 15, q = lane >> 4;
    int h = grp * 16 + li;
    int c0 = q * 8;
    #pragma unroll
    for (int j = 0; j < 8; j++) {
      int c = c0 + j;
      w1sw[e * 8 + j] = f2bf((c < 9) ? W1[c * 128 + h] : 0.f);
    }
  } else {
    // w2 A-frags (16x16x32): entry e = (wr*16+ks*4+td)*64 + lane; 8 halves each
    int e = (b - 3) * 256 + t;       // 2048 entries x 8 halves = 32KB
    if (e < 2048) {
      int lane = e & 63, grp = e >> 6;
      int wr = grp >> 4, sub = grp & 15;
      int ks = sub >> 2, td = sub & 3;
      int li = lane & 15, q = lane >> 4;
      int d = wr * 64 + td * 16 + li;
      int h0 = ks * 32 + q * 8;
      #pragma unroll
      for (int j = 0; j < 8; j++)
        w2sw[e * 8 + j] = f2bf(W2[(h0 + j) * 128 + d]);
    }
  }
}

// ---------------- main ----------------
// LDS: one 32768 B arena.  Lifetimes:
//   [0, 4608)  Xs   raw f32 X block              (b0 .. bfb)
//   whole      Hb   H^T bf16, XOR-swizzled 16B chunks   (bfb .. b2)
//   [0,16896)  P    pooled partials f32          (b2 .. end)
__global__ __launch_bounds__(256, 5) void poly_main_k(
    const float* __restrict__ X, const void* __restrict__ mask,
    const float* __restrict__ b1g, const float* __restrict__ b2g,
    const unsigned short* __restrict__ w1sw, const unsigned short* __restrict__ w2sw,
    const int* __restrict__ flagp, float* __restrict__ out)
{
  __shared__ __align__(16) unsigned char smem[32768];
  float*          Xs = (float*)smem;
  unsigned short* Hb = (unsigned short*)smem;
  float*          P  = (float*)smem;

  const int tid  = threadIdx.x;
  const int lane = tid & 63;
  const int w    = tid >> 6;
  const int wr   = w >> 1, wc = w & 1;   // wr = h/d half, wc = polyline in block
  const int li   = lane & 15, q = lane >> 4;

  // ---- mask: direct loads; all 4 per lane sit in one 64B line (byte case) ----
  float mf[4];
  {
    int flag = *flagp;
    long long mb = (long long)blockIdx.x * 128 + wc * 64 + li;
    if (flag) {
      const unsigned char* mp = (const unsigned char*)mask;
      #pragma unroll
      for (int tm = 0; tm < 4; tm++) mf[tm] = mp[mb + tm * 16] ? 0.f : -4e9f;
    } else {
      const int* mp = (const int*)mask;
      #pragma unroll
      for (int tm = 0; tm < 4; tm++) mf[tm] = mp[mb + tm * 16] ? 0.f : -4e9f;
    }
  }

  // ---- stage X: 288 float4 coalesced global -> LDS b128 ----
  {
    const f32x4* xg = (const f32x4*)(X + (long long)blockIdx.x * 1152);
    f32x4* xl = (f32x4*)Xs;
    xl[tid] = xg[tid];
    if (tid < 32) xl[tid + 256] = xg[tid + 256];
  }
  __syncthreads();  // b0: Xs ready

  // ---- layer-1 B-frags from Xs: B[m][k], k=q*8+j, only c<9 nonzero ----
  bf16x8 bx[4];
  #pragma unroll
  for (int tm = 0; tm < 4; tm++) {
    int m = wc * 64 + tm * 16 + li;
    const float* xr = Xs + m * 9;
    union { bf16x8 v; unsigned int u[4]; } uu;
    uu.u[0] = uu.u[1] = uu.u[2] = uu.u[3] = 0u;
    if (q == 0) {
      uu.u[0] = pack_bf2(xr[0], xr[1]); uu.u[1] = pack_bf2(xr[2], xr[3]);
      uu.u[2] = pack_bf2(xr[4], xr[5]); uu.u[3] = pack_bf2(xr[6], xr[7]);
    } else if (q == 1) {
      uu.u[0] = pack_bf2(xr[8], 0.f);
    }
    bx[tm] = uu.v;
  }
  __syncthreads();  // bfb: all Xs reads done -> Hb may overwrite arena

  // ---- layer 1: D1[h][m], acc INIT = b1 (bias folded into MFMA C) ----
  f32x4 acc1[4][4];
  #pragma unroll
  for (int th = 0; th < 4; th++) {
    f32x4 bv = *(const f32x4*)(b1g + wr * 64 + th * 16 + q * 4);
    #pragma unroll
    for (int tm = 0; tm < 4; tm++) acc1[th][tm] = bv;
  }
  {
    bf16x8 a1[4];
    #pragma unroll
    for (int th = 0; th < 4; th++)
      a1[th] = *(const bf16x8*)(w1sw + ((wr * 4 + th) * 64 + lane) * 8);
    #pragma unroll
    for (int th = 0; th < 4; th++)
      #pragma unroll
      for (int tm = 0; tm < 4; tm++)
        acc1[th][tm] = MFMA32(a1[th], bx[tm], acc1[th][tm]);
  }

  // ---- epilogue 1: relu (packed max), pack, swizzled H^T write ----
  // write chunk index (16B units): (wr*8 + th*2 + (q>>1)) ^ li, inner (q&1)*8B
  #pragma unroll
  for (int th = 0; th < 4; th++) {
    #pragma unroll
    for (int tm = 0; tm < 4; tm++) {
      int m = wc * 64 + tm * 16 + li;
      f32x4 v = vmax4(acc1[th][tm], f32x4{0.f, 0.f, 0.f, 0.f});
      uint2 hv;
      hv.x = pack_bf2(v[0], v[1]);
      hv.y = pack_bf2(v[2], v[3]);
      int chunk = (wr * 8 + th * 2 + (q >> 1)) ^ li;
      *(uint2*)(Hb + m * 128 + chunk * 8 + (q & 1) * 4) = hv;
    }
  }
  __syncthreads();  // b1: Hb ready

  // ---- layer 2: D2[d][m], acc INIT = b2; A from global frags, B from Hb ----
  f32x4 acc2[4][4];
  #pragma unroll
  for (int td = 0; td < 4; td++) {
    f32x4 bv = *(const f32x4*)(b2g + wr * 64 + td * 16 + q * 4);
    #pragma unroll
    for (int tm = 0; tm < 4; tm++) acc2[td][tm] = bv;
  }
  #pragma unroll
  for (int ks = 0; ks < 4; ks++) {
    bf16x8 a2[4], bb[4];
    #pragma unroll
    for (int td = 0; td < 4; td++)
      a2[td] = *(const bf16x8*)(w2sw + (((wr * 16 + ks * 4 + td) * 64) + lane) * 8);
    #pragma unroll
    for (int tm = 0; tm < 4; tm++) {
      int m = wc * 64 + tm * 16 + li;
      int chunk = (ks * 4 + q) ^ li;             // read swizzle, 16B aligned
      bb[tm] = *(const bf16x8*)(Hb + m * 128 + chunk * 8);
    }
    #pragma unroll
    for (int td = 0; td < 4; td++)
      #pragma unroll
      for (int tm = 0; tm < 4; tm++)
        acc2[td][tm] = MFMA32(a2[td], bb[tm], acc2[td][tm]);
  }

  // ---- pool over 4 m-tiles, packed: max_tm(acc2 + mf[tm]) (bias already in) ----
  f32x4 pooled[4];
  #pragma unroll
  for (int td = 0; td < 4; td++) {
    f32x4 v = acc2[td][0] + mf[0];
    v = vmax4(v, acc2[td][1] + mf[1]);
    v = vmax4(v, acc2[td][2] + mf[2]);
    v = vmax4(v, acc2[td][3] + mf[3]);
    pooled[td] = v;
  }

  __syncthreads();  // b2: all Hb reads done -> reuse arena as P
  // P[wc*16+li][d] f32, row stride 132 (pad breaks 2^k bank stride)
  #pragma unroll
  for (int td = 0; td < 4; td++)
    *(f32x4*)(P + (wc * 16 + li) * 132 + wr * 64 + td * 16 + q * 4) = pooled[td];
  __syncthreads();  // b3: P ready

  // ---- final: reduce 16 li-partials per (poly,d), coalesced full-line store ----
  {
    int p = tid >> 7, d = tid & 127;
    const float* Pp = P + p * (16 * 132) + d;
    float v = Pp[0];
    #pragma unroll
    for (int j = 1; j < 16; j++) v = fmaxf(v, Pp[j * 132]);
    if (v < -1e8f) v = 0.f;
    out[(long long)blockIdx.x * 256 + tid] = v;
  }
}

extern "C" void kernel_launch(void* const* d_in, const int* in_sizes, int n_in,
                              void* d_out, int out_size, void* d_ws, size_t ws_size,
                              hipStream_t stream) {
  const float* X    = (const float*)d_in[0];
  const void*  mask = d_in[1];
  const float* W1   = (const float*)d_in[2];
  const float* b1   = (const float*)d_in[3];
  const float* W2   = (const float*)d_in[4];
  const float* b2   = (const float*)d_in[5];
  float* out = (float*)d_out;

  unsigned short* w1sw = (unsigned short*)d_ws;
  unsigned short* w2sw = (unsigned short*)((char*)d_ws + 8192);
  int* flag            = (int*)((char*)d_ws + 40960);

  prep1<<<11, 256, 0, stream>>>(W1, W2, mask, w1sw, w2sw, flag);
  poly_main_k<<<8192, 256, 0, stream>>>(X, mask, b1, b2, w1sw, w2sw, flag, out);
}

// Round 6
// 162.491 us; speedup vs baseline: 1.1109x; 1.1109x over previous
//
#include <hip/hip_runtime.h>

// PolylineEncoder: h = relu(X@W1+b1); feat = h@W2+b2; masked max over N=64 points.
// B=32 P=512 N=64 C=9 H=128.  Block = 2 polylines (128 points), grid 8192.
// R6: register-lean restructure so 5 waves/EU fits WITHOUT spilling
// (R5's launch_bounds(256,5) + 128 live regs spilled 18 regs/thread -> 146MB
// scratch writes).  Layer-1 th-outer (acc live = 16 regs), layer-2 tm-outer
// with incremental pooling (acc 16 + pooled 16).  Keeps R5's XOR-swizzled
// 32KB LDS arena, packed f32 ops, direct mask loads, frag-swizzled weights.

using bf16x8 = __attribute__((ext_vector_type(8))) short;
using f32x4  = __attribute__((ext_vector_type(4))) float;

#define MFMA32(A,B,C) __builtin_amdgcn_mfma_f32_16x16x32_bf16((A),(B),(C),0,0,0)

__device__ __forceinline__ f32x4 vmax4(f32x4 a, f32x4 b) {
  return __builtin_elementwise_max(a, b);
}

__device__ __forceinline__ unsigned short f2bf(float f) {
  union { float f; unsigned int u; } v; v.f = f;
  unsigned int r = v.u + 0x7fffu + ((v.u >> 16) & 1u);  // RNE
  return (unsigned short)(r >> 16);
}

// pack two floats to bf16x2 (round-half-up) via v_perm: 3 VALU per 2 elems
__device__ __forceinline__ unsigned int pack_bf2(float a, float b) {
  union { float f; unsigned int u; } ua, ub; ua.f = a; ub.f = b;
  return __builtin_amdgcn_perm(ub.u + 0x8000u, ua.u + 0x8000u, 0x07060302u);
}

// ---------------- prep1: mask sniff + frag-swizzled weights ----------------
// ws: w1sw @0 (8KB) | w2sw @8192 (32KB) | flag @40960
__global__ void prep1(const float* __restrict__ W1, const float* __restrict__ W2,
                      const void* __restrict__ mask,
                      unsigned short* __restrict__ w1sw, unsigned short* __restrict__ w2sw,
                      int* __restrict__ flag) {
  int b = blockIdx.x, t = threadIdx.x;
  if (b == 0) {                      // mask storage sniff over 4096 bytes
    __shared__ int cnt;
    if (t == 0) cnt = 0;
    __syncthreads();
    const unsigned char* mb = (const unsigned char*)mask;
    int local = 0;
    for (int i = t * 16; i < t * 16 + 16; i++) local += (mb[i] != 0) ? 1 : 0;
    atomicAdd(&cnt, local);
    __syncthreads();
    if (t == 0) *flag = (cnt > 2800) ? 1 : 0;   // 1 = byte-wise mask, else int32-wise
  } else if (b <= 2) {
    // w1 A-frags (16x16x32): entry e = (wr*4+th)*64 + lane; h=(e>>6)*16+(lane&15)
    int e = (b - 1) * 256 + t;       // 512 entries x 8 halves = 8KB
    int lane = e & 63, grp = e >> 6;
    int li = lane & 15, q = lane >> 4;
    int h = grp * 16 + li;
    int c0 = q * 8;
    #pragma unroll
    for (int j = 0; j < 8; j++) {
      int c = c0 + j;
      w1sw[e * 8 + j] = f2bf((c < 9) ? W1[c * 128 + h] : 0.f);
    }
  } else {
    // w2 A-frags (16x16x32): entry e = (wr*16+ks*4+td)*64 + lane; 8 halves each
    int e = (b - 3) * 256 + t;       // 2048 entries x 8 halves = 32KB
    if (e < 2048) {
      int lane = e & 63, grp = e >> 6;
      int wr = grp >> 4, sub = grp & 15;
      int ks = sub >> 2, td = sub & 3;
      int li = lane & 15, q = lane >> 4;
      int d = wr * 64 + td * 16 + li;
      int h0 = ks * 32 + q * 8;
      #pragma unroll
      for (int j = 0; j < 8; j++)
        w2sw[e * 8 + j] = f2bf(W2[(h0 + j) * 128 + d]);
    }
  }
}

// ---------------- main ----------------
// LDS: one 32768 B arena.  Lifetimes:
//   [0, 4608)  Xs  raw f32 X block                   (b0 .. bfb)
//   whole      Hb  H^T bf16, XOR-swizzled 16B chunks (bfb .. b2)
//   [0,16896)  P   pooled partials f32               (b2 .. end)
__global__ __launch_bounds__(256, 5) void poly_main_k(
    const float* __restrict__ X, const void* __restrict__ mask,
    const float* __restrict__ b1g, const float* __restrict__ b2g,
    const unsigned short* __restrict__ w1sw, const unsigned short* __restrict__ w2sw,
    const int* __restrict__ flagp, float* __restrict__ out)
{
  __shared__ __align__(16) unsigned char smem[32768];
  float*          Xs = (float*)smem;
  unsigned short* Hb = (unsigned short*)smem;
  float*          P  = (float*)smem;

  const int tid  = threadIdx.x;
  const int lane = tid & 63;
  const int w    = tid >> 6;
  const int wr   = w >> 1, wc = w & 1;   // wr = h/d half, wc = polyline in block
  const int li   = lane & 15, q = lane >> 4;

  // ---- mask: direct loads; all 4 per lane sit in one 64B line (byte case) ----
  float mf[4];
  {
    int flag = *flagp;
    long long mb = (long long)blockIdx.x * 128 + wc * 64 + li;
    if (flag) {
      const unsigned char* mp = (const unsigned char*)mask;
      #pragma unroll
      for (int tm = 0; tm < 4; tm++) mf[tm] = mp[mb + tm * 16] ? 0.f : -4e9f;
    } else {
      const int* mp = (const int*)mask;
      #pragma unroll
      for (int tm = 0; tm < 4; tm++) mf[tm] = mp[mb + tm * 16] ? 0.f : -4e9f;
    }
  }

  // ---- stage X: 288 float4 coalesced global -> LDS b128 ----
  {
    const f32x4* xg = (const f32x4*)(X + (long long)blockIdx.x * 1152);
    f32x4* xl = (f32x4*)Xs;
    xl[tid] = xg[tid];
    if (tid < 32) xl[tid + 256] = xg[tid + 256];
  }
  __syncthreads();  // b0: Xs ready

  // ---- layer-1 B-frags from Xs: B[m][k], k=q*8+j, only c<9 nonzero ----
  bf16x8 bx[4];
  #pragma unroll
  for (int tm = 0; tm < 4; tm++) {
    int m = wc * 64 + tm * 16 + li;
    const float* xr = Xs + m * 9;
    union { bf16x8 v; unsigned int u[4]; } uu;
    uu.u[0] = uu.u[1] = uu.u[2] = uu.u[3] = 0u;
    if (q == 0) {
      uu.u[0] = pack_bf2(xr[0], xr[1]); uu.u[1] = pack_bf2(xr[2], xr[3]);
      uu.u[2] = pack_bf2(xr[4], xr[5]); uu.u[3] = pack_bf2(xr[6], xr[7]);
    } else if (q == 1) {
      uu.u[0] = pack_bf2(xr[8], 0.f);
    }
    bx[tm] = uu.v;
  }
  __syncthreads();  // bfb: all Xs reads done -> Hb may overwrite arena

  // ---- layer 1, th-outer: acc live = 16 regs; bias folded into MFMA C ----
  #pragma unroll
  for (int th = 0; th < 4; th++) {
    bf16x8 a1 = *(const bf16x8*)(w1sw + ((wr * 4 + th) * 64 + lane) * 8);
    f32x4 bv = *(const f32x4*)(b1g + wr * 64 + th * 16 + q * 4);
    f32x4 acc[4];
    #pragma unroll
    for (int tm = 0; tm < 4; tm++) acc[tm] = bv;
    #pragma unroll
    for (int tm = 0; tm < 4; tm++) acc[tm] = MFMA32(a1, bx[tm], acc[tm]);
    // epilogue: relu (packed max), pack, swizzled H^T write
    // write chunk (16B units): (wr*8 + th*2 + (q>>1)) ^ li, inner (q&1)*8B
    #pragma unroll
    for (int tm = 0; tm < 4; tm++) {
      int m = wc * 64 + tm * 16 + li;
      f32x4 v = vmax4(acc[tm], f32x4{0.f, 0.f, 0.f, 0.f});
      uint2 hv;
      hv.x = pack_bf2(v[0], v[1]);
      hv.y = pack_bf2(v[2], v[3]);
      int chunk = (wr * 8 + th * 2 + (q >> 1)) ^ li;
      *(uint2*)(Hb + m * 128 + chunk * 8 + (q & 1) * 4) = hv;
    }
  }
  __syncthreads();  // b1: Hb ready

  // ---- layer 2, tm-outer with incremental pool: acc 16 + pooled 16 regs ----
  f32x4 pooled[4];
  #pragma unroll
  for (int tm = 0; tm < 4; tm++) {
    int m = wc * 64 + tm * 16 + li;
    f32x4 acc[4];
    #pragma unroll
    for (int td = 0; td < 4; td++) acc[td] = f32x4{0.f, 0.f, 0.f, 0.f};
    #pragma unroll
    for (int ks = 0; ks < 4; ks++) {
      int chunk = (ks * 4 + q) ^ li;             // read swizzle, 16B aligned
      bf16x8 bb = *(const bf16x8*)(Hb + m * 128 + chunk * 8);
      #pragma unroll
      for (int td = 0; td < 4; td++) {
        bf16x8 a2 = *(const bf16x8*)(w2sw + (((wr * 16 + ks * 4 + td) * 64) + lane) * 8);
        acc[td] = MFMA32(a2, bb, acc[td]);
      }
    }
    if (tm == 0) {
      #pragma unroll
      for (int td = 0; td < 4; td++) pooled[td] = acc[td] + mf[0];
    } else {
      #pragma unroll
      for (int td = 0; td < 4; td++) pooled[td] = vmax4(pooled[td], acc[td] + mf[tm]);
    }
  }
  // bias after max (uniform over m)
  #pragma unroll
  for (int td = 0; td < 4; td++)
    pooled[td] += *(const f32x4*)(b2g + wr * 64 + td * 16 + q * 4);

  __syncthreads();  // b2: all Hb reads done -> reuse arena as P
  // P[wc*16+li][d] f32, row stride 132 (pad breaks 2^k bank stride)
  #pragma unroll
  for (int td = 0; td < 4; td++)
    *(f32x4*)(P + (wc * 16 + li) * 132 + wr * 64 + td * 16 + q * 4) = pooled[td];
  __syncthreads();  // b3: P ready

  // ---- final: reduce 16 li-partials per (poly,d), coalesced full-line store ----
  {
    int p = tid >> 7, d = tid & 127;
    const float* Pp = P + p * (16 * 132) + d;
    float v = Pp[0];
    #pragma unroll
    for (int j = 1; j < 16; j++) v = fmaxf(v, Pp[j * 132]);
    if (v < -1e8f) v = 0.f;
    out[(long long)blockIdx.x * 256 + tid] = v;
  }
}

extern "C" void kernel_launch(void* const* d_in, const int* in_sizes, int n_in,
                              void* d_out, int out_size, void* d_ws, size_t ws_size,
                              hipStream_t stream) {
  const float* X    = (const float*)d_in[0];
  const void*  mask = d_in[1];
  const float* W1   = (const float*)d_in[2];
  const float* b1   = (const float*)d_in[3];
  const float* W2   = (const float*)d_in[4];
  const float* b2   = (const float*)d_in[5];
  float* out = (float*)d_out;

  unsigned short* w1sw = (unsigned short*)d_ws;
  unsigned short* w2sw = (unsigned short*)((char*)d_ws + 8192);
  int* flag            = (int*)((char*)d_ws + 40960);

  prep1<<<11, 256, 0, stream>>>(W1, W2, mask, w1sw, w2sw, flag);
  poly_main_k<<<8192, 256, 0, stream>>>(X, mask, b1, b2, w1sw, w2sw, flag, out);
}

// Round 7
// 138.906 us; speedup vs baseline: 1.2996x; 1.1698x over previous
//
#include <hip/hip_runtime.h>

// PolylineEncoder: h = relu(X@W1+b1); feat = h@W2+b2; masked max over N=64 points.
// B=32 P=512 N=64 C=9 H=128.  Block = 2 polylines (128 points), grid 8192.
// R7 = R6 with __launch_bounds__(256,4): at 5 waves/EU the compiler's legal
// hoist of the 16 tm-invariant w2 frags (64 regs) blew the ~102-reg budget and
// spilled ~100MB to scratch (R5: 156MB, R6: 111MB WRITE_SIZE).  Budget 128 fits
// the hoist (R4 proved it: 10MB writes).  Keeps XOR-swizzled 32KB LDS arena,
// folded bias, packed f32 epilogue/pool, frag-swizzled weights, direct mask.

using bf16x8 = __attribute__((ext_vector_type(8))) short;
using f32x4  = __attribute__((ext_vector_type(4))) float;

#define MFMA32(A,B,C) __builtin_amdgcn_mfma_f32_16x16x32_bf16((A),(B),(C),0,0,0)

__device__ __forceinline__ f32x4 vmax4(f32x4 a, f32x4 b) {
  return __builtin_elementwise_max(a, b);
}

__device__ __forceinline__ unsigned short f2bf(float f) {
  union { float f; unsigned int u; } v; v.f = f;
  unsigned int r = v.u + 0x7fffu + ((v.u >> 16) & 1u);  // RNE
  return (unsigned short)(r >> 16);
}

// pack two floats to bf16x2 (round-half-up) via v_perm: 3 VALU per 2 elems
__device__ __forceinline__ unsigned int pack_bf2(float a, float b) {
  union { float f; unsigned int u; } ua, ub; ua.f = a; ub.f = b;
  return __builtin_amdgcn_perm(ub.u + 0x8000u, ua.u + 0x8000u, 0x07060302u);
}

// ---------------- prep1: mask sniff + frag-swizzled weights ----------------
// ws: w1sw @0 (8KB) | w2sw @8192 (32KB) | flag @40960
__global__ void prep1(const float* __restrict__ W1, const float* __restrict__ W2,
                      const void* __restrict__ mask,
                      unsigned short* __restrict__ w1sw, unsigned short* __restrict__ w2sw,
                      int* __restrict__ flag) {
  int b = blockIdx.x, t = threadIdx.x;
  if (b == 0) {                      // mask storage sniff over 4096 bytes
    __shared__ int cnt;
    if (t == 0) cnt = 0;
    __syncthreads();
    const unsigned char* mb = (const unsigned char*)mask;
    int local = 0;
    for (int i = t * 16; i < t * 16 + 16; i++) local += (mb[i] != 0) ? 1 : 0;
    atomicAdd(&cnt, local);
    __syncthreads();
    if (t == 0) *flag = (cnt > 2800) ? 1 : 0;   // 1 = byte-wise mask, else int32-wise
  } else if (b <= 2) {
    // w1 A-frags (16x16x32): entry e = (wr*4+th)*64 + lane; h=(e>>6)*16+(lane&15)
    int e = (b - 1) * 256 + t;       // 512 entries x 8 halves = 8KB
    int lane = e & 63, grp = e >> 6;
    int li = lane & 15, q = lane >> 4;
    int h = grp * 16 + li;
    int c0 = q * 8;
    #pragma unroll
    for (int j = 0; j < 8; j++) {
      int c = c0 + j;
      w1sw[e * 8 + j] = f2bf((c < 9) ? W1[c * 128 + h] : 0.f);
    }
  } else {
    // w2 A-frags (16x16x32): entry e = (wr*16+ks*4+td)*64 + lane; 8 halves each
    int e = (b - 3) * 256 + t;       // 2048 entries x 8 halves = 32KB
    if (e < 2048) {
      int lane = e & 63, grp = e >> 6;
      int wr = grp >> 4, sub = grp & 15;
      int ks = sub >> 2, td = sub & 3;
      int li = lane & 15, q = lane >> 4;
      int d = wr * 64 + td * 16 + li;
      int h0 = ks * 32 + q * 8;
      #pragma unroll
      for (int j = 0; j < 8; j++)
        w2sw[e * 8 + j] = f2bf(W2[(h0 + j) * 128 + d]);
    }
  }
}

// ---------------- main ----------------
// LDS: one 32768 B arena.  Lifetimes:
//   [0, 4608)  Xs  raw f32 X block                   (b0 .. bfb)
//   whole      Hb  H^T bf16, XOR-swizzled 16B chunks (bfb .. b2)
//   [0,16896)  P   pooled partials f32               (b2 .. end)
__global__ __launch_bounds__(256, 4) void poly_main_k(
    const float* __restrict__ X, const void* __restrict__ mask,
    const float* __restrict__ b1g, const float* __restrict__ b2g,
    const unsigned short* __restrict__ w1sw, const unsigned short* __restrict__ w2sw,
    const int* __restrict__ flagp, float* __restrict__ out)
{
  __shared__ __align__(16) unsigned char smem[32768];
  float*          Xs = (float*)smem;
  unsigned short* Hb = (unsigned short*)smem;
  float*          P  = (float*)smem;

  const int tid  = threadIdx.x;
  const int lane = tid & 63;
  const int w    = tid >> 6;
  const int wr   = w >> 1, wc = w & 1;   // wr = h/d half, wc = polyline in block
  const int li   = lane & 15, q = lane >> 4;

  // ---- mask: direct loads; all 4 per lane sit in one 64B line (byte case) ----
  float mf[4];
  {
    int flag = *flagp;
    long long mb = (long long)blockIdx.x * 128 + wc * 64 + li;
    if (flag) {
      const unsigned char* mp = (const unsigned char*)mask;
      #pragma unroll
      for (int tm = 0; tm < 4; tm++) mf[tm] = mp[mb + tm * 16] ? 0.f : -4e9f;
    } else {
      const int* mp = (const int*)mask;
      #pragma unroll
      for (int tm = 0; tm < 4; tm++) mf[tm] = mp[mb + tm * 16] ? 0.f : -4e9f;
    }
  }

  // ---- stage X: 288 float4 coalesced global -> LDS b128 ----
  {
    const f32x4* xg = (const f32x4*)(X + (long long)blockIdx.x * 1152);
    f32x4* xl = (f32x4*)Xs;
    xl[tid] = xg[tid];
    if (tid < 32) xl[tid + 256] = xg[tid + 256];
  }
  __syncthreads();  // b0: Xs ready

  // ---- layer-1 B-frags from Xs: B[m][k], k=q*8+j, only c<9 nonzero ----
  bf16x8 bx[4];
  #pragma unroll
  for (int tm = 0; tm < 4; tm++) {
    int m = wc * 64 + tm * 16 + li;
    const float* xr = Xs + m * 9;
    union { bf16x8 v; unsigned int u[4]; } uu;
    uu.u[0] = uu.u[1] = uu.u[2] = uu.u[3] = 0u;
    if (q == 0) {
      uu.u[0] = pack_bf2(xr[0], xr[1]); uu.u[1] = pack_bf2(xr[2], xr[3]);
      uu.u[2] = pack_bf2(xr[4], xr[5]); uu.u[3] = pack_bf2(xr[6], xr[7]);
    } else if (q == 1) {
      uu.u[0] = pack_bf2(xr[8], 0.f);
    }
    bx[tm] = uu.v;
  }
  __syncthreads();  // bfb: all Xs reads done -> Hb may overwrite arena

  // ---- layer 1, th-outer: bias folded into MFMA C ----
  #pragma unroll
  for (int th = 0; th < 4; th++) {
    bf16x8 a1 = *(const bf16x8*)(w1sw + ((wr * 4 + th) * 64 + lane) * 8);
    f32x4 bv = *(const f32x4*)(b1g + wr * 64 + th * 16 + q * 4);
    f32x4 acc[4];
    #pragma unroll
    for (int tm = 0; tm < 4; tm++) acc[tm] = bv;
    #pragma unroll
    for (int tm = 0; tm < 4; tm++) acc[tm] = MFMA32(a1, bx[tm], acc[tm]);
    // epilogue: relu (packed max), pack, swizzled H^T write
    // write chunk (16B units): (wr*8 + th*2 + (q>>1)) ^ li, inner (q&1)*8B
    #pragma unroll
    for (int tm = 0; tm < 4; tm++) {
      int m = wc * 64 + tm * 16 + li;
      f32x4 v = vmax4(acc[tm], f32x4{0.f, 0.f, 0.f, 0.f});
      uint2 hv;
      hv.x = pack_bf2(v[0], v[1]);
      hv.y = pack_bf2(v[2], v[3]);
      int chunk = (wr * 8 + th * 2 + (q >> 1)) ^ li;
      *(uint2*)(Hb + m * 128 + chunk * 8 + (q & 1) * 4) = hv;
    }
  }
  __syncthreads();  // b1: Hb ready

  // ---- layer 2, tm-outer with incremental pool ----
  f32x4 pooled[4];
  #pragma unroll
  for (int tm = 0; tm < 4; tm++) {
    int m = wc * 64 + tm * 16 + li;
    f32x4 acc[4];
    #pragma unroll
    for (int td = 0; td < 4; td++) acc[td] = f32x4{0.f, 0.f, 0.f, 0.f};
    #pragma unroll
    for (int ks = 0; ks < 4; ks++) {
      int chunk = (ks * 4 + q) ^ li;             // read swizzle, 16B aligned
      bf16x8 bb = *(const bf16x8*)(Hb + m * 128 + chunk * 8);
      #pragma unroll
      for (int td = 0; td < 4; td++) {
        bf16x8 a2 = *(const bf16x8*)(w2sw + (((wr * 16 + ks * 4 + td) * 64) + lane) * 8);
        acc[td] = MFMA32(a2, bb, acc[td]);
      }
    }
    if (tm == 0) {
      #pragma unroll
      for (int td = 0; td < 4; td++) pooled[td] = acc[td] + mf[0];
    } else {
      #pragma unroll
      for (int td = 0; td < 4; td++) pooled[td] = vmax4(pooled[td], acc[td] + mf[tm]);
    }
  }
  // bias after max (uniform over m)
  #pragma unroll
  for (int td = 0; td < 4; td++)
    pooled[td] += *(const f32x4*)(b2g + wr * 64 + td * 16 + q * 4);

  __syncthreads();  // b2: all Hb reads done -> reuse arena as P
  // P[wc*16+li][d] f32, row stride 132 (pad breaks 2^k bank stride)
  #pragma unroll
  for (int td = 0; td < 4; td++)
    *(f32x4*)(P + (wc * 16 + li) * 132 + wr * 64 + td * 16 + q * 4) = pooled[td];
  __syncthreads();  // b3: P ready

  // ---- final: reduce 16 li-partials per (poly,d), coalesced full-line store ----
  {
    int p = tid >> 7, d = tid & 127;
    const float* Pp = P + p * (16 * 132) + d;
    float v = Pp[0];
    #pragma unroll
    for (int j = 1; j < 16; j++) v = fmaxf(v, Pp[j * 132]);
    if (v < -1e8f) v = 0.f;
    out[(long long)blockIdx.x * 256 + tid] = v;
  }
}

extern "C" void kernel_launch(void* const* d_in, const int* in_sizes, int n_in,
                              void* d_out, int out_size, void* d_ws, size_t ws_size,
                              hipStream_t stream) {
  const float* X    = (const float*)d_in[0];
  const void*  mask = d_in[1];
  const float* W1   = (const float*)d_in[2];
  const float* b1   = (const float*)d_in[3];
  const float* W2   = (const float*)d_in[4];
  const float* b2   = (const float*)d_in[5];
  float* out = (float*)d_out;

  unsigned short* w1sw = (unsigned short*)d_ws;
  unsigned short* w2sw = (unsigned short*)((char*)d_ws + 8192);
  int* flag            = (int*)((char*)d_ws + 40960);

  prep1<<<11, 256, 0, stream>>>(W1, W2, mask, w1sw, w2sw, flag);
  poly_main_k<<<8192, 256, 0, stream>>>(X, mask, b1, b2, w1sw, w2sw, flag, out);
}